// Round 9
// baseline (553.901 us; speedup 1.0000x reference)
//
#include <hip/hip_runtime.h>
#include <stdint.h>

#define NSAMP 16384
#define NSITE 2048
#define BM 256
#define BN 256
#define BK 32
#define NT_M (NSAMP / BM)   // 64
#define NT_N (NSITE / BN)   // 8

typedef _Float16 f16x8 __attribute__((ext_vector_type(8)));
typedef float f32x16 __attribute__((ext_vector_type(16)));

__device__ __forceinline__ unsigned short f2h(float f) {
  _Float16 h = (_Float16)f;
  return __builtin_bit_cast(unsigned short, h);
}
__device__ __forceinline__ float h2f(unsigned short u) {
  return (float)__builtin_bit_cast(_Float16, u);
}

__device__ __forceinline__ void gload_lds16(const void* g, void* l) {
  __builtin_amdgcn_global_load_lds(
      (const __attribute__((address_space(1))) void*)g,
      (__attribute__((address_space(3))) void*)l, 16, 0, 0);
}

#define SBAR() __builtin_amdgcn_sched_barrier(0)
#define BAR()  do { SBAR(); __builtin_amdgcn_s_barrier(); SBAR(); } while (0)
#define WLGKM(N) do { asm volatile("s_waitcnt lgkmcnt(" #N ")" ::: "memory"); SBAR(); } while (0)
#define WVM(N)   do { asm volatile("s_waitcnt vmcnt(" #N ")" ::: "memory"); SBAR(); } while (0)

// ---------------------------------------------------------------------------
// Packed fragment-major layout for an [R x 2048] fp16 matrix M:
//   frag (rbG, kb) is 1 KiB: lane l holds M[rbG*32 + (l&31)][kb*16 + (l>>5)*8 + e]
//   short index = ((rbG*128 + kb)*64 + lane)*8 + e
// This makes (a) staging/loads contiguous 1KiB per wave-instruction and
// (b) LDS fragment reads uniform-base + lane*16 (zero bank conflicts).
// ---------------------------------------------------------------------------

// W packed: W[j][i] = fp16(kernel[tri(j,i)]) for i<j else 0, frag-major.
__global__ void build_w_kernel(const float* __restrict__ kern,
                               unsigned short* __restrict__ Wp) {
  const int idx = blockIdx.x * blockDim.x + threadIdx.x;  // one 8-short group
  const int lane = idx & 63;
  const int kb = (idx >> 6) & 127;
  const int rbG = idx >> 13;
  const int j = rbG * 32 + (lane & 31);
  const int i0 = kb * 16 + (lane >> 5) * 8;
  const long long tri = (long long)j * (j - 1) / 2;
  unsigned short v[8];
#pragma unroll
  for (int e = 0; e < 8; ++e) {
    const int i = i0 + e;
    float f = (i < j) ? kern[tri + i] : 0.0f;
    v[e] = f2h(f);
  }
  ushort4* dst = (ushort4*)(Wp + (size_t)idx * 8);
  dst[0] = make_ushort4(v[0], v[1], v[2], v[3]);
  dst[1] = make_ushort4(v[4], v[5], v[6], v[7]);
}

// X: build BOTH frag-major packed (pass-1 A operand) and row-major fp16.
__global__ void build_x_kernel(const float* __restrict__ x,
                               unsigned short* __restrict__ Xp,
                               unsigned short* __restrict__ Xrow) {
  const int idx = blockIdx.x * blockDim.x + threadIdx.x;  // row-major 8-group
  const int row = idx >> 8;
  const int c8 = idx & 255;
  const float4 v0 = ((const float4*)x)[(size_t)idx * 2];
  const float4 v1 = ((const float4*)x)[(size_t)idx * 2 + 1];
  const ushort4 h0 = make_ushort4(f2h(v0.x), f2h(v0.y), f2h(v0.z), f2h(v0.w));
  const ushort4 h1 = make_ushort4(f2h(v1.x), f2h(v1.y), f2h(v1.z), f2h(v1.w));
  ushort4* dr = (ushort4*)(Xrow + (size_t)idx * 8);
  dr[0] = h0;
  dr[1] = h1;
  const int rbG = row >> 5, kb = c8 >> 1;
  const int lane = (c8 & 1) * 32 + (row & 31);
  ushort4* dp = (ushort4*)(Xp + (((size_t)rbG * 128 + kb) * 64 + lane) * 8);
  dp[0] = h0;
  dp[1] = h1;
}

// 256x256 tile, 8 waves (2M x 4N), wave tile 128x64, 32x32x16 fp16 MFMA.
// A: frag-major global -> LDS DMA ring-3 (16KB/slot, 48KB total), 0-conflict reads.
// W: frag-major global -> registers directly (1KiB coalesced L2 loads), 1-step dbuf.
// Counted waits: lgkm 4/0 chunks, end-of-step vmcnt(2). One barrier per K-step.
template <int EPI>
__global__ __launch_bounds__(512, 2) void gemm_pass(
    const unsigned short* __restrict__ Ap, const unsigned short* __restrict__ Wp,
    const unsigned short* __restrict__ Xrow, unsigned short* __restrict__ Pp,
    float* __restrict__ out) {
  __shared__ unsigned short lds[3 * 8192];  // 48 KiB

  const int bid = blockIdx.x;
  // blocks 0..255: nt = 7,6,5,4 (heavy); 256..511: nt = 0,1,2,3 (light)
  const int cohort = (bid >> 6) & 3;
  const int nt = (bid >> 8) ? cohort : (7 - cohort);
  const int mt = bid & 63;
  const int m0 = mt * BM, n0 = nt * BN;

  const int tid = threadIdx.x, lane = tid & 63, wid = tid >> 6;
  const int wm = wid >> 2;   // 0..1: rows wm*128..
  const int wn = wid & 3;    // 0..3: cols wn*64..
  const int l32 = lane & 31, hi2 = lane >> 5;
  const int nkt = 8 * (nt + 1);

  f32x16 acc[4][2] = {};  // [mb][nb], 128 VGPR

  // --- A staging: thread covers frags fi = wid and 8+wid of each slot ---
  const int rbG0 = m0 >> 5;
  const int fi0 = wid, fi1 = 8 + wid;
  const unsigned short* srcA0 =
      Ap + (((size_t)(rbG0 + (fi0 >> 1)) * 128 + (fi0 & 1)) * 64 + lane) * 8;
  const unsigned short* srcA1 =
      Ap + (((size_t)(rbG0 + (fi1 >> 1)) * 128 + (fi1 & 1)) * 64 + lane) * 8;
  const int dA0 = fi0 * 1024 + lane * 16;
  const int dA1 = fi1 * 1024 + lane * 16;
  auto STAGE = [&](int kidx, int slotbase) {
    gload_lds16(srcA0 + (size_t)kidx * 1024, (char*)lds + slotbase + dA0);
    gload_lds16(srcA1 + (size_t)kidx * 1024, (char*)lds + slotbase + dA1);
  };

  // --- B pointers (frag-major W, straight to regs) ---
  const int cbG = nt * 8 + wn * 2;
  const unsigned short* wp00 = Wp + (((size_t)(cbG + 0) * 128 + 0) * 64 + lane) * 8;
  const unsigned short* wp01 = Wp + (((size_t)(cbG + 0) * 128 + 1) * 64 + lane) * 8;
  const unsigned short* wp10 = Wp + (((size_t)(cbG + 1) * 128 + 0) * 64 + lane) * 8;
  const unsigned short* wp11 = Wp + (((size_t)(cbG + 1) * 128 + 1) * 64 + lane) * 8;

  int sl0 = 0, sl1 = 16384, sl2 = 32768;

  // prologue: A(0), B(0), A(1); wait leaves A(1) in flight
  STAGE(0, sl0);
  SBAR();
  f16x8 b00 = *(const f16x8*)(wp00);
  f16x8 b01 = *(const f16x8*)(wp01);
  f16x8 b10 = *(const f16x8*)(wp10);
  f16x8 b11 = *(const f16x8*)(wp11);
  SBAR();
  STAGE(1, sl1);
  WVM(2);
  BAR();

  for (int t = 0; t < nkt; ++t) {
    // ds_read A fragments (8 x b128, uniform base + lane*16: conflict-free)
    f16x8 fa0[4], fa1[4];
#pragma unroll
    for (int mb = 0; mb < 4; ++mb)
      fa0[mb] = *(const f16x8*)((char*)lds + sl0 + ((wm * 4 + mb) * 2 + 0) * 1024 + lane * 16);
#pragma unroll
    for (int mb = 0; mb < 4; ++mb)
      fa1[mb] = *(const f16x8*)((char*)lds + sl0 + ((wm * 4 + mb) * 2 + 1) * 1024 + lane * 16);
    SBAR();
    // issue next-step B loads, then next-next A stage (order matters for vmcnt)
    const bool hasB = (t + 1 < nkt);
    f16x8 n00, n01, n10, n11;
    if (hasB) {
      n00 = *(const f16x8*)(wp00 + (size_t)(t + 1) * 1024);
      n01 = *(const f16x8*)(wp01 + (size_t)(t + 1) * 1024);
      n10 = *(const f16x8*)(wp10 + (size_t)(t + 1) * 1024);
      n11 = *(const f16x8*)(wp11 + (size_t)(t + 1) * 1024);
    }
    SBAR();
    if (t + 2 < nkt) STAGE(t + 2, sl2);
    WLGKM(4);  // fa0 ready
    __builtin_amdgcn_s_setprio(1);
#pragma unroll
    for (int mb = 0; mb < 4; ++mb) {
      acc[mb][0] = __builtin_amdgcn_mfma_f32_32x32x16_f16(fa0[mb], b00, acc[mb][0], 0, 0, 0);
      acc[mb][1] = __builtin_amdgcn_mfma_f32_32x32x16_f16(fa0[mb], b10, acc[mb][1], 0, 0, 0);
    }
    WLGKM(0);  // fa1 ready
#pragma unroll
    for (int mb = 0; mb < 4; ++mb) {
      acc[mb][0] = __builtin_amdgcn_mfma_f32_32x32x16_f16(fa1[mb], b01, acc[mb][0], 0, 0, 0);
      acc[mb][1] = __builtin_amdgcn_mfma_f32_32x32x16_f16(fa1[mb], b11, acc[mb][1], 0, 0, 0);
    }
    __builtin_amdgcn_s_setprio(0);
    if (hasB) { b00 = n00; b01 = n01; b10 = n10; b11 = n11; }
    if (t + 1 < nkt) {
      if (t + 2 < nkt) { WVM(2); } else { WVM(0); }  // A(t+1)+B(t+1) landed
      BAR();
    }
    const int tmp = sl0; sl0 = sl1; sl1 = sl2; sl2 = tmp;
  }

  BAR();  // all waves done with ring before epilogue reuses LDS

  // C/D layout 32x32: col = lane&31, row = (reg&3)+8*(reg>>2)+4*(lane>>5)
  const int ebase = wid * 4096;  // per-wave 4KB scratch inside the 48KB
  if (EPI == 0) {
#pragma unroll
    for (int mb = 0; mb < 4; ++mb) {
      const int growb = m0 + wm * 128 + mb * 32;
      // p = acc * x (fp16), transposed into per-wave LDS [32 rows][64 cols]
#pragma unroll
      for (int nb = 0; nb < 2; ++nb)
#pragma unroll
        for (int r = 0; r < 16; ++r) {
          const int row = (r & 3) + 8 * (r >> 2) + 4 * hi2;
          const int col = nb * 32 + l32;
          const unsigned short xv =
              Xrow[(size_t)(growb + row) * NSITE + n0 + wn * 64 + col];
          const unsigned short pv = f2h(acc[mb][nb][r] * h2f(xv));
          *(volatile unsigned short*)((char*)lds + ebase + row * 128 + col * 2) = pv;
        }
      WLGKM(0);  // wave-local: writes visible to own reads
      const int rbG = growb >> 5;
#pragma unroll
      for (int kbl = 0; kbl < 4; ++kbl) {
        f16x8 fr = *(const f16x8*)((char*)lds + ebase + l32 * 128 + kbl * 32 + hi2 * 16);
        const int kbG = ((n0 + wn * 64) >> 4) + kbl;
        *(f16x8*)(Pp + (((size_t)rbG * 128 + kbG) * 64 + lane) * 8) = fr;
      }
      WLGKM(0);  // reads done before next mb overwrites the region
    }
  } else {
#pragma unroll
    for (int mb = 0; mb < 4; ++mb) {
      const int growb = m0 + wm * 128 + mb * 32;
#pragma unroll
      for (int r = 0; r < 16; ++r) {
        const int row = (r & 3) + 8 * (r >> 2) + 4 * hi2;
        const int grow = growb + row;
        const size_t xb = (size_t)grow * NSITE + n0 + wn * 64 + l32;
        float s = acc[mb][0][r] * h2f(Xrow[xb]) + acc[mb][1][r] * h2f(Xrow[xb + 32]);
        s += __shfl_xor(s, 1);
        s += __shfl_xor(s, 2);
        s += __shfl_xor(s, 4);
        s += __shfl_xor(s, 8);
        s += __shfl_xor(s, 16);
        if (l32 == 0) atomicAdd(&out[grow], s);
      }
    }
  }
}

extern "C" void kernel_launch(void* const* d_in, const int* in_sizes, int n_in,
                              void* d_out, int out_size, void* d_ws, size_t ws_size,
                              hipStream_t stream) {
  const float* x = (const float*)d_in[0];
  const float* kern = (const float*)d_in[1];
  float* out = (float*)d_out;

  unsigned short* Wp   = (unsigned short*)d_ws;             // N*N fp16 packed
  unsigned short* Xp   = Wp + (size_t)NSITE * NSITE;        // NS*N packed
  unsigned short* Xrow = Xp + (size_t)NSAMP * NSITE;        // NS*N row-major
  unsigned short* P1   = Xrow + (size_t)NSAMP * NSITE;      // NS*N packed
  unsigned short* P2   = P1 + (size_t)NSAMP * NSITE;        // NS*N packed

  hipMemsetAsync(d_out, 0, (size_t)NSAMP * sizeof(float), stream);
  build_w_kernel<<<(NSITE * NSITE / 8) / 256, 256, 0, stream>>>(kern, Wp);
  build_x_kernel<<<(NSAMP * NSITE / 8) / 256, 256, 0, stream>>>(x, Xp, Xrow);

  // pass 1: z1 = x @ W^T ; P1 = pack(fp16(z1 * x))
  gemm_pass<0><<<NT_M * NT_N, 512, 0, stream>>>(Xp, Wp, Xrow, P1, nullptr);
  // pass 2: z2 = P1 @ W^T ; P2 = pack(fp16(z2 * x))
  gemm_pass<0><<<NT_M * NT_N, 512, 0, stream>>>(P1, Wp, Xrow, P2, nullptr);
  // pass 3: z3 = P2 @ W^T ; out[n] = sum_j z3 * x
  gemm_pass<1><<<NT_M * NT_N, 512, 0, stream>>>(P2, Wp, Xrow, nullptr, out);
}